// Round 3
// baseline (1776.258 us; speedup 1.0000x reference)
//
#include <hip/hip_runtime.h>
#include <cmath>

#define D  128   // D_EDGE
#define DR 64    // D_RBF
#define NB 32    // nodes per block in stage1

__device__ __forceinline__ float ssp_f(float x) {
  // softplus(x) - log(2), numerically stable
  float m = fmaxf(x, 0.0f);
  float t = __expf(-fabsf(x));
  return m + __logf(1.0f + t) - 0.69314718055994531f;
}

// ---------------------------------------------------------------------------
// stage0: W_eff[o][r] = sum_d W_cat[o][d] * W_rbf[d][r]   (128 x 64)
//         b_eff[o]    = b_cat[o] + sum_d b_rbf[d] * W_cat[o][d]
// ---------------------------------------------------------------------------
__global__ __launch_bounds__(256) void stage0_kernel(
    const float* __restrict__ W_rbf, const float* __restrict__ b_rbf,
    const float* __restrict__ W_cat, const float* __restrict__ b_cat,
    float* __restrict__ weff, float* __restrict__ beff)
{
  int gid = blockIdx.x * 256 + threadIdx.x;
  if (gid < D * DR) {
    int o = gid >> 6;      // output channel
    int r = gid & 63;      // rbf channel
    float acc = 0.0f;
    #pragma unroll 8
    for (int d = 0; d < D; ++d)
      acc = fmaf(W_cat[o * 384 + d], W_rbf[d * DR + r], acc);
    weff[gid] = acc;
  }
  if (gid < D) {
    float acc = b_cat[gid];
    #pragma unroll 8
    for (int d = 0; d < D; ++d)
      acc = fmaf(b_rbf[d], W_cat[gid * 384 + d], acc);
    beff[gid] = acc;
  }
}

// ---------------------------------------------------------------------------
// stage1: Pj[n][o] = sum_d vi[n][d] * W_cat[o][128+d]
//         Pi[n][o] = sum_d vi[n][d] * W_cat[o][256+d]
// ---------------------------------------------------------------------------
__global__ __launch_bounds__(256) void stage1_kernel(
    const float* __restrict__ vi, const float* __restrict__ W_cat,
    float* __restrict__ Pj, float* __restrict__ Pi, int N)
{
  __shared__ float vrow[NB * D];
  int base = blockIdx.x * NB;
  int t = threadIdx.x;
  for (int idx = t * 4; idx < NB * D; idx += 1024) {
    int n = base + (idx >> 7);
    float4 v = make_float4(0.f, 0.f, 0.f, 0.f);
    if (n < N) v = *(const float4*)&vi[(long)n * D + (idx & 127)];
    *(float4*)&vrow[idx] = v;
  }
  __syncthreads();

  int o     = t & 127;
  int which = t >> 7;   // 0 -> Pj (cols 128:256), 1 -> Pi (cols 256:384)
  const float* w = W_cat + (long)o * 384 + 128 + which * 128;
  float* P = which ? Pi : Pj;

  float acc[NB];
  #pragma unroll
  for (int n = 0; n < NB; ++n) acc[n] = 0.0f;

  for (int dd = 0; dd < D; dd += 4) {
    float4 wv = *(const float4*)&w[dd];
    #pragma unroll
    for (int n = 0; n < NB; ++n) {
      float4 v = *(const float4*)&vrow[n * D + dd];  // wave-uniform -> broadcast
      acc[n] = fmaf(wv.x, v.x, acc[n]);
      acc[n] = fmaf(wv.y, v.y, acc[n]);
      acc[n] = fmaf(wv.z, v.z, acc[n]);
      acc[n] = fmaf(wv.w, v.w, acc[n]);
    }
  }
  #pragma unroll
  for (int n = 0; n < NB; ++n) {
    int nn = base + n;
    if (nn < N) P[(long)nn * D + o] = acc[n];
  }
}

// ---------------------------------------------------------------------------
// edge kernel: 256 edges/block, 4 output chunks of 32.
// Phase 1 (lane-per-edge): GEMM chunk -> LDS stage (stride 33, conflict-free).
// Phase 2 (8 lanes/edge): coalesced Pj/Pi gathers + coalesced float4 store.
// Pipelining: p=0 gathers for chunk cb are issued BEFORE phase-1 of cb
// (hidden under ~4096 cy of FMA); inside phase 2 a depth-2 rotating prefetch
// keeps 2 gather pairs in flight; at p==7 the next chunk's p=0 is issued.
// ---------------------------------------------------------------------------
__global__ __launch_bounds__(256, 4) void edge_kernel(
    const float* __restrict__ rbf, const int* __restrict__ eidx,
    const float* __restrict__ weff, const float* __restrict__ beff,
    const float* __restrict__ Pj, const float* __restrict__ Pi,
    float* __restrict__ out, int E)
{
  __shared__ float stage[256 * 33];
  __shared__ int jbuf[256], ibuf[256];

  const int t = threadIdx.x;
  const long base = (long)blockIdx.x * 256;
  const long e = base + t;
  const bool valid = e < (long)E;

  float4 rb[16];
  if (valid) {
    const float4* rp = (const float4*)(rbf + e * DR);
    #pragma unroll
    for (int c = 0; c < 16; ++c) rb[c] = rp[c];
    ibuf[t] = eidx[e];       // edge_index[0] -> h_i -> Pi
    jbuf[t] = eidx[E + e];   // edge_index[1] -> h_j -> Pj
  } else {
    #pragma unroll
    for (int c = 0; c < 16; ++c) rb[c] = make_float4(0.f, 0.f, 0.f, 0.f);
    ibuf[t] = 0;
    jbuf[t] = 0;
  }
  __syncthreads();   // indices visible to all phase-2 roles

  // phase-2 role constants for this thread
  const int q  = t >> 3;        // edge-slot within a 32-edge group
  const int oo = (t & 7) * 4;   // float offset within the 32-output chunk
  const int j0 = jbuf[q];       // p=0 edge indices (constant across chunks)
  const int i0 = ibuf[q];

  // prefetch (cb=0, p=0) gathers — lands under phase-1 FMA
  float4 pjc = *(const float4*)&Pj[(long)j0 * D + oo];
  float4 pic = *(const float4*)&Pi[(long)i0 * D + oo];

  for (int cb = 0; cb < 4; ++cb) {
    const int ob0 = cb * 32;

    // ---- phase 1: 32 dot-products for own edge, staged to LDS ----
    for (int o = 0; o < 32; o += 4) {
      const int ob = ob0 + o;
      float4 b4 = *(const float4*)&beff[ob];
      float acc0 = b4.x, acc1 = b4.y, acc2 = b4.z, acc3 = b4.w;
      const float4* w0 = (const float4*)&weff[(ob + 0) * DR];
      const float4* w1 = (const float4*)&weff[(ob + 1) * DR];
      const float4* w2 = (const float4*)&weff[(ob + 2) * DR];
      const float4* w3 = (const float4*)&weff[(ob + 3) * DR];
      #pragma unroll
      for (int c = 0; c < 16; ++c) {
        float4 r4 = rb[c];
        float4 wa = w0[c], wb = w1[c], wc = w2[c], wd = w3[c];
        acc0 = fmaf(wa.x, r4.x, acc0); acc0 = fmaf(wa.y, r4.y, acc0);
        acc0 = fmaf(wa.z, r4.z, acc0); acc0 = fmaf(wa.w, r4.w, acc0);
        acc1 = fmaf(wb.x, r4.x, acc1); acc1 = fmaf(wb.y, r4.y, acc1);
        acc1 = fmaf(wb.z, r4.z, acc1); acc1 = fmaf(wb.w, r4.w, acc1);
        acc2 = fmaf(wc.x, r4.x, acc2); acc2 = fmaf(wc.y, r4.y, acc2);
        acc2 = fmaf(wc.z, r4.z, acc2); acc2 = fmaf(wc.w, r4.w, acc2);
        acc3 = fmaf(wd.x, r4.x, acc3); acc3 = fmaf(wd.y, r4.y, acc3);
        acc3 = fmaf(wd.z, r4.z, acc3); acc3 = fmaf(wd.w, r4.w, acc3);
      }
      stage[t * 33 + o + 0] = acc0;
      stage[t * 33 + o + 1] = acc1;
      stage[t * 33 + o + 2] = acc2;
      stage[t * 33 + o + 3] = acc3;
    }
    __syncthreads();

    // ---- phase 2: combine staged GEMM + gathers, rotating prefetch ----
    for (int p = 0; p < 8; ++p) {
      float4 pjn, pin;
      if (p < 7) {                         // next p of this chunk
        const int el = (p + 1) * 32 + q;
        const int jn = jbuf[el], in_ = ibuf[el];
        pjn = *(const float4*)&Pj[(long)jn * D + ob0 + oo];
        pin = *(const float4*)&Pi[(long)in_ * D + ob0 + oo];
      } else if (cb < 3) {                 // p=0 of next chunk
        pjn = *(const float4*)&Pj[(long)j0 * D + ob0 + 32 + oo];
        pin = *(const float4*)&Pi[(long)i0 * D + ob0 + 32 + oo];
      }
      const int el = p * 32 + q;
      const long eg = base + el;
      const float* sp = &stage[el * 33 + oo];
      float4 o4;
      o4.x = ssp_f(pjc.x + pic.x + sp[0]);
      o4.y = ssp_f(pjc.y + pic.y + sp[1]);
      o4.z = ssp_f(pjc.z + pic.z + sp[2]);
      o4.w = ssp_f(pjc.w + pic.w + sp[3]);
      if (eg < (long)E) *(float4*)&out[eg * D + ob0 + oo] = o4;
      pjc = pjn; pic = pin;
    }
    __syncthreads();
  }
}

// ---------------------------------------------------------------------------
// Fallback (only if d_ws is too small for Pj/Pi): 3 additive passes over out.
// ---------------------------------------------------------------------------
template<int K, int WS, int WOFF, bool GATHER, bool INIT, bool FINAL>
__global__ __launch_bounds__(256) void pass_kernel(
    const float* __restrict__ src, const int* __restrict__ gidx,
    const float* __restrict__ W, const float* __restrict__ beff,
    float* __restrict__ out, int E)
{
  int e = blockIdx.x * 256 + threadIdx.x;
  if (e >= E) return;
  long row = GATHER ? (long)gidx[e] : (long)e;

  float4 rv[K / 4];
  const float4* sp = (const float4*)(src + row * K);
  #pragma unroll
  for (int c = 0; c < K / 4; ++c) rv[c] = sp[c];

  float* orow = out + (long)e * D;
  for (int ob = 0; ob < D; ob += 4) {
    float acc[4];
    if (INIT) {
      float4 b4 = *(const float4*)&beff[ob];
      acc[0] = b4.x; acc[1] = b4.y; acc[2] = b4.z; acc[3] = b4.w;
    } else {
      float4 p4 = *(const float4*)&orow[ob];
      acc[0] = p4.x; acc[1] = p4.y; acc[2] = p4.z; acc[3] = p4.w;
    }
    #pragma unroll
    for (int k = 0; k < 4; ++k) {
      const float4* w = (const float4*)&W[(long)(ob + k) * WS + WOFF];
      float a = acc[k];
      #pragma unroll
      for (int c = 0; c < K / 4; ++c) {
        float4 w4 = w[c]; float4 r4 = rv[c];
        a = fmaf(w4.x, r4.x, a); a = fmaf(w4.y, r4.y, a);
        a = fmaf(w4.z, r4.z, a); a = fmaf(w4.w, r4.w, a);
      }
      acc[k] = a;
    }
    float4 o4;
    o4.x = FINAL ? ssp_f(acc[0]) : acc[0];
    o4.y = FINAL ? ssp_f(acc[1]) : acc[1];
    o4.z = FINAL ? ssp_f(acc[2]) : acc[2];
    o4.w = FINAL ? ssp_f(acc[3]) : acc[3];
    *(float4*)&orow[ob] = o4;
  }
}

// ---------------------------------------------------------------------------
extern "C" void kernel_launch(void* const* d_in, const int* in_sizes, int n_in,
                              void* d_out, int out_size, void* d_ws, size_t ws_size,
                              hipStream_t stream)
{
  const float* vi    = (const float*)d_in[0];
  const float* rbf   = (const float*)d_in[1];
  const float* W_rbf = (const float*)d_in[2];
  const float* b_rbf = (const float*)d_in[3];
  const float* W_cat = (const float*)d_in[4];
  const float* b_cat = (const float*)d_in[5];
  const int*   eidx  = (const int*)d_in[6];

  const int N = in_sizes[0] / D;
  const int E = in_sizes[6] / 2;
  float* out = (float*)d_out;

  float* ws   = (float*)d_ws;
  float* weff = ws;                 // 128*64 = 8192 floats
  float* beff = ws + D * DR;        // 128 floats (ends at 8320)
  float* Pj   = ws + 8448;          // N*128 floats, 16B-aligned
  float* Pi   = Pj + (size_t)N * D; // N*128 floats
  size_t need = (8448 + 2 * (size_t)N * D) * sizeof(float);

  stage0_kernel<<<32, 256, 0, stream>>>(W_rbf, b_rbf, W_cat, b_cat, weff, beff);

  int eblocks = (E + 255) / 256;
  if (ws_size >= need) {
    stage1_kernel<<<(N + NB - 1) / NB, 256, 0, stream>>>(vi, W_cat, Pj, Pi, N);
    edge_kernel<<<eblocks, 256, 0, stream>>>(rbf, eidx, weff, beff, Pj, Pi, out, E);
  } else {
    // 3-pass fallback, needs only ~34 KB of ws (weff + beff)
    pass_kernel<DR, DR, 0,  false, true,  false><<<eblocks, 256, 0, stream>>>(rbf, nullptr,  weff,  beff, out, E);
    pass_kernel<D, 384, 128, true, false, false><<<eblocks, 256, 0, stream>>>(vi,  eidx + E, W_cat, beff, out, E);
    pass_kernel<D, 384, 256, true, false, true ><<<eblocks, 256, 0, stream>>>(vi,  eidx,     W_cat, beff, out, E);
  }
}

// Round 4
// 551.633 us; speedup vs baseline: 3.2200x; 3.2200x over previous
//
#include <hip/hip_runtime.h>
#include <cmath>

#define D  128   // D_EDGE
#define DR 64    // D_RBF
#define NB 32    // nodes per block in stage1

__device__ __forceinline__ float ssp_f(float x) {
  // softplus(x) - log(2), numerically stable
  float m = fmaxf(x, 0.0f);
  float t = __expf(-fabsf(x));
  return m + __logf(1.0f + t) - 0.69314718055994531f;
}

// ---------------------------------------------------------------------------
// stage0: W_eff[o][r] = sum_d W_cat[o][d] * W_rbf[d][r]   (128 x 64)
//         b_eff[o]    = b_cat[o] + sum_d b_rbf[d] * W_cat[o][d]
// ---------------------------------------------------------------------------
__global__ __launch_bounds__(256) void stage0_kernel(
    const float* __restrict__ W_rbf, const float* __restrict__ b_rbf,
    const float* __restrict__ W_cat, const float* __restrict__ b_cat,
    float* __restrict__ weff, float* __restrict__ beff)
{
  int gid = blockIdx.x * 256 + threadIdx.x;
  if (gid < D * DR) {
    int o = gid >> 6;      // output channel
    int r = gid & 63;      // rbf channel
    float acc = 0.0f;
    #pragma unroll 8
    for (int d = 0; d < D; ++d)
      acc = fmaf(W_cat[o * 384 + d], W_rbf[d * DR + r], acc);
    weff[gid] = acc;
  }
  if (gid < D) {
    float acc = b_cat[gid];
    #pragma unroll 8
    for (int d = 0; d < D; ++d)
      acc = fmaf(b_rbf[d], W_cat[gid * 384 + d], acc);
    beff[gid] = acc;
  }
}

// ---------------------------------------------------------------------------
// stage1: Pj[n][o] = sum_d vi[n][d] * W_cat[o][128+d]
//         Pi[n][o] = sum_d vi[n][d] * W_cat[o][256+d]
// ---------------------------------------------------------------------------
__global__ __launch_bounds__(256) void stage1_kernel(
    const float* __restrict__ vi, const float* __restrict__ W_cat,
    float* __restrict__ Pj, float* __restrict__ Pi, int N)
{
  __shared__ float vrow[NB * D];
  int base = blockIdx.x * NB;
  int t = threadIdx.x;
  for (int idx = t * 4; idx < NB * D; idx += 1024) {
    int n = base + (idx >> 7);
    float4 v = make_float4(0.f, 0.f, 0.f, 0.f);
    if (n < N) v = *(const float4*)&vi[(long)n * D + (idx & 127)];
    *(float4*)&vrow[idx] = v;
  }
  __syncthreads();

  int o     = t & 127;
  int which = t >> 7;   // 0 -> Pj (cols 128:256), 1 -> Pi (cols 256:384)
  const float* w = W_cat + (long)o * 384 + 128 + which * 128;
  float* P = which ? Pi : Pj;

  float acc[NB];
  #pragma unroll
  for (int n = 0; n < NB; ++n) acc[n] = 0.0f;

  for (int dd = 0; dd < D; dd += 4) {
    float4 wv = *(const float4*)&w[dd];
    #pragma unroll
    for (int n = 0; n < NB; ++n) {
      float4 v = *(const float4*)&vrow[n * D + dd];  // wave-uniform -> broadcast
      acc[n] = fmaf(wv.x, v.x, acc[n]);
      acc[n] = fmaf(wv.y, v.y, acc[n]);
      acc[n] = fmaf(wv.z, v.z, acc[n]);
      acc[n] = fmaf(wv.w, v.w, acc[n]);
    }
  }
  #pragma unroll
  for (int n = 0; n < NB; ++n) {
    int nn = base + n;
    if (nn < N) P[(long)nn * D + o] = acc[n];
  }
}

// ---------------------------------------------------------------------------
// edge kernel: 256 edges/block, 4 output chunks of 32.
// Phase 1 (lane-per-edge): GEMM chunk -> LDS stage (stride 33, conflict-free).
// Phase 2 (8 lanes/edge): coalesced Pj/Pi gathers + coalesced float4 store.
// Pipelining: p=0 gathers for chunk cb issued BEFORE phase-1 of cb; inside
// phase 2 a depth-2 rotating prefetch keeps the next gather pair in flight.
// NOTE: no min-waves launch bound — this kernel needs ~116 live VGPRs
// (rb[16] is 64 alone); capping VGPRs spills rb to scratch (R3: 5.4 GB fetch).
// ---------------------------------------------------------------------------
__global__ __launch_bounds__(256) void edge_kernel(
    const float* __restrict__ rbf, const int* __restrict__ eidx,
    const float* __restrict__ weff, const float* __restrict__ beff,
    const float* __restrict__ Pj, const float* __restrict__ Pi,
    float* __restrict__ out, int E)
{
  __shared__ float stage[256 * 33];
  __shared__ int jbuf[256], ibuf[256];

  const int t = threadIdx.x;
  const long base = (long)blockIdx.x * 256;
  const long e = base + t;
  const bool valid = e < (long)E;

  float4 rb[16];
  if (valid) {
    const float4* rp = (const float4*)(rbf + e * DR);
    #pragma unroll
    for (int c = 0; c < 16; ++c) rb[c] = rp[c];
    ibuf[t] = eidx[e];       // edge_index[0] -> h_i -> Pi
    jbuf[t] = eidx[E + e];   // edge_index[1] -> h_j -> Pj
  } else {
    #pragma unroll
    for (int c = 0; c < 16; ++c) rb[c] = make_float4(0.f, 0.f, 0.f, 0.f);
    ibuf[t] = 0;
    jbuf[t] = 0;
  }
  __syncthreads();   // indices visible to all phase-2 roles

  // phase-2 role constants for this thread
  const int q  = t >> 3;        // edge-slot within a 32-edge group
  const int oo = (t & 7) * 4;   // float offset within the 32-output chunk
  const int j0 = jbuf[q];       // p=0 edge indices (constant across chunks)
  const int i0 = ibuf[q];

  // prefetch (cb=0, p=0) gathers — lands under phase-1 FMA
  float4 pjc = *(const float4*)&Pj[(long)j0 * D + oo];
  float4 pic = *(const float4*)&Pi[(long)i0 * D + oo];

  for (int cb = 0; cb < 4; ++cb) {
    const int ob0 = cb * 32;

    // ---- phase 1: 32 dot-products for own edge, staged to LDS ----
    for (int o = 0; o < 32; o += 4) {
      const int ob = ob0 + o;
      float4 b4 = *(const float4*)&beff[ob];
      float acc0 = b4.x, acc1 = b4.y, acc2 = b4.z, acc3 = b4.w;
      const float4* w0 = (const float4*)&weff[(ob + 0) * DR];
      const float4* w1 = (const float4*)&weff[(ob + 1) * DR];
      const float4* w2 = (const float4*)&weff[(ob + 2) * DR];
      const float4* w3 = (const float4*)&weff[(ob + 3) * DR];
      #pragma unroll
      for (int c = 0; c < 16; ++c) {
        float4 r4 = rb[c];
        float4 wa = w0[c], wb = w1[c], wc = w2[c], wd = w3[c];
        acc0 = fmaf(wa.x, r4.x, acc0); acc0 = fmaf(wa.y, r4.y, acc0);
        acc0 = fmaf(wa.z, r4.z, acc0); acc0 = fmaf(wa.w, r4.w, acc0);
        acc1 = fmaf(wb.x, r4.x, acc1); acc1 = fmaf(wb.y, r4.y, acc1);
        acc1 = fmaf(wb.z, r4.z, acc1); acc1 = fmaf(wb.w, r4.w, acc1);
        acc2 = fmaf(wc.x, r4.x, acc2); acc2 = fmaf(wc.y, r4.y, acc2);
        acc2 = fmaf(wc.z, r4.z, acc2); acc2 = fmaf(wc.w, r4.w, acc2);
        acc3 = fmaf(wd.x, r4.x, acc3); acc3 = fmaf(wd.y, r4.y, acc3);
        acc3 = fmaf(wd.z, r4.z, acc3); acc3 = fmaf(wd.w, r4.w, acc3);
      }
      stage[t * 33 + o + 0] = acc0;
      stage[t * 33 + o + 1] = acc1;
      stage[t * 33 + o + 2] = acc2;
      stage[t * 33 + o + 3] = acc3;
    }
    __syncthreads();

    // ---- phase 2: combine staged GEMM + gathers, rotating prefetch ----
    for (int p = 0; p < 8; ++p) {
      float4 pjn = pjc, pin = pic;
      if (p < 7) {                         // next p of this chunk
        const int el = (p + 1) * 32 + q;
        const int jn = jbuf[el], in_ = ibuf[el];
        pjn = *(const float4*)&Pj[(long)jn * D + ob0 + oo];
        pin = *(const float4*)&Pi[(long)in_ * D + ob0 + oo];
      } else if (cb < 3) {                 // p=0 of next chunk
        pjn = *(const float4*)&Pj[(long)j0 * D + ob0 + 32 + oo];
        pin = *(const float4*)&Pi[(long)i0 * D + ob0 + 32 + oo];
      }
      const int el = p * 32 + q;
      const long eg = base + el;
      const float* sp = &stage[el * 33 + oo];
      float4 o4;
      o4.x = ssp_f(pjc.x + pic.x + sp[0]);
      o4.y = ssp_f(pjc.y + pic.y + sp[1]);
      o4.z = ssp_f(pjc.z + pic.z + sp[2]);
      o4.w = ssp_f(pjc.w + pic.w + sp[3]);
      if (eg < (long)E) *(float4*)&out[eg * D + ob0 + oo] = o4;
      pjc = pjn; pic = pin;
    }
    __syncthreads();
  }
}

// ---------------------------------------------------------------------------
// Fallback (only if d_ws is too small for Pj/Pi): 3 additive passes over out.
// ---------------------------------------------------------------------------
template<int K, int WS, int WOFF, bool GATHER, bool INIT, bool FINAL>
__global__ __launch_bounds__(256) void pass_kernel(
    const float* __restrict__ src, const int* __restrict__ gidx,
    const float* __restrict__ W, const float* __restrict__ beff,
    float* __restrict__ out, int E)
{
  int e = blockIdx.x * 256 + threadIdx.x;
  if (e >= E) return;
  long row = GATHER ? (long)gidx[e] : (long)e;

  float4 rv[K / 4];
  const float4* sp = (const float4*)(src + row * K);
  #pragma unroll
  for (int c = 0; c < K / 4; ++c) rv[c] = sp[c];

  float* orow = out + (long)e * D;
  for (int ob = 0; ob < D; ob += 4) {
    float acc[4];
    if (INIT) {
      float4 b4 = *(const float4*)&beff[ob];
      acc[0] = b4.x; acc[1] = b4.y; acc[2] = b4.z; acc[3] = b4.w;
    } else {
      float4 p4 = *(const float4*)&orow[ob];
      acc[0] = p4.x; acc[1] = p4.y; acc[2] = p4.z; acc[3] = p4.w;
    }
    #pragma unroll
    for (int k = 0; k < 4; ++k) {
      const float4* w = (const float4*)&W[(long)(ob + k) * WS + WOFF];
      float a = acc[k];
      #pragma unroll
      for (int c = 0; c < K / 4; ++c) {
        float4 w4 = w[c]; float4 r4 = rv[c];
        a = fmaf(w4.x, r4.x, a); a = fmaf(w4.y, r4.y, a);
        a = fmaf(w4.z, r4.z, a); a = fmaf(w4.w, r4.w, a);
      }
      acc[k] = a;
    }
    float4 o4;
    o4.x = FINAL ? ssp_f(acc[0]) : acc[0];
    o4.y = FINAL ? ssp_f(acc[1]) : acc[1];
    o4.z = FINAL ? ssp_f(acc[2]) : acc[2];
    o4.w = FINAL ? ssp_f(acc[3]) : acc[3];
    *(float4*)&orow[ob] = o4;
  }
}

// ---------------------------------------------------------------------------
extern "C" void kernel_launch(void* const* d_in, const int* in_sizes, int n_in,
                              void* d_out, int out_size, void* d_ws, size_t ws_size,
                              hipStream_t stream)
{
  const float* vi    = (const float*)d_in[0];
  const float* rbf   = (const float*)d_in[1];
  const float* W_rbf = (const float*)d_in[2];
  const float* b_rbf = (const float*)d_in[3];
  const float* W_cat = (const float*)d_in[4];
  const float* b_cat = (const float*)d_in[5];
  const int*   eidx  = (const int*)d_in[6];

  const int N = in_sizes[0] / D;
  const int E = in_sizes[6] / 2;
  float* out = (float*)d_out;

  float* ws   = (float*)d_ws;
  float* weff = ws;                 // 128*64 = 8192 floats
  float* beff = ws + D * DR;        // 128 floats (ends at 8320)
  float* Pj   = ws + 8448;          // N*128 floats, 16B-aligned
  float* Pi   = Pj + (size_t)N * D; // N*128 floats
  size_t need = (8448 + 2 * (size_t)N * D) * sizeof(float);

  stage0_kernel<<<32, 256, 0, stream>>>(W_rbf, b_rbf, W_cat, b_cat, weff, beff);

  int eblocks = (E + 255) / 256;
  if (ws_size >= need) {
    stage1_kernel<<<(N + NB - 1) / NB, 256, 0, stream>>>(vi, W_cat, Pj, Pi, N);
    edge_kernel<<<eblocks, 256, 0, stream>>>(rbf, eidx, weff, beff, Pj, Pi, out, E);
  } else {
    // 3-pass fallback, needs only ~34 KB of ws (weff + beff)
    pass_kernel<DR, DR, 0,  false, true,  false><<<eblocks, 256, 0, stream>>>(rbf, nullptr,  weff,  beff, out, E);
    pass_kernel<D, 384, 128, true, false, false><<<eblocks, 256, 0, stream>>>(vi,  eidx + E, W_cat, beff, out, E);
    pass_kernel<D, 384, 256, true, false, true ><<<eblocks, 256, 0, stream>>>(vi,  eidx,     W_cat, beff, out, E);
  }
}